// Round 2
// baseline (1451.754 us; speedup 1.0000x reference)
//
#include <hip/hip_runtime.h>
#include <hip/hip_bf16.h>

#define DEVI __device__ __forceinline__

// order-preserving float->uint encoding for atomicMax (0 == -inf sentinel)
DEVI unsigned fenc(float f){ unsigned u=__float_as_uint(f); return (u & 0x80000000u) ? ~u : (u | 0x80000000u); }
DEVI float fdec(unsigned u){ unsigned v = (u & 0x80000000u) ? (u & 0x7FFFFFFFu) : ~u; return __uint_as_float(v); }

// ---------------------------------------------------------------------------
// Projection GEMM + fused attention-logit epilogue (all f32).
// Z[N,KOUT] = A[N,KIN] @ W[KIN,KOUT]   (Z optional)
// el[n,h] = sum_f acc[n,h*F+f]*al[h*F+f]   (optional)
// er[n,h] likewise with ar (optional).
// Block: 256 threads, ROWS = 256/KOUT rows per block, thread = one out elem.
// ---------------------------------------------------------------------------
template<int KIN, int KOUT, int H>
__global__ __launch_bounds__(256)
void gemm_attn(const float* __restrict__ A, const float* __restrict__ W,
               float* __restrict__ Z,
               float* __restrict__ el_out, const float* __restrict__ al,
               float* __restrict__ er_out, const float* __restrict__ ar,
               int N)
{
  constexpr int ROWS = 256 / KOUT;
  constexpr int F = KOUT / H;
  __shared__ float a_lds[ROWS * KIN];
  const int row0 = blockIdx.x * ROWS;
  for (int i = threadIdx.x; i < ROWS * KIN; i += 256) {
    int rr = i / KIN;
    int row = row0 + rr;
    a_lds[i] = (row < N) ? A[(size_t)row * KIN + (i - rr * KIN)] : 0.f;
  }
  __syncthreads();
  const int r = threadIdx.x / KOUT;
  const int c = threadIdx.x - r * KOUT;
  const int row = row0 + r;
  const float* arow = &a_lds[r * KIN];
  float acc = 0.f;
#pragma unroll 8
  for (int k = 0; k < KIN; ++k) acc = fmaf(arow[k], W[k * KOUT + c], acc);
  if (Z != nullptr && row < N) Z[(size_t)row * KOUT + c] = acc;
  // attention dots: butterfly reduce across the F lanes of each head group
  // (F = 32 or 64; groups are lane-aligned inside the 64-lane wave)
  if (el_out != nullptr) {
    float v = acc * al[c];
#pragma unroll
    for (int m = 1; m < F; m <<= 1) v += __shfl_xor(v, m, 64);
    if (row < N && (c & (F - 1)) == 0) el_out[row * H + (c / F)] = v;
  }
  if (er_out != nullptr) {
    float v = acc * ar[c];
#pragma unroll
    for (int m = 1; m < F; m <<= 1) v += __shfl_xor(v, m, 64);
    if (row < N && (c & (F - 1)) == 0) er_out[row * H + (c / F)] = v;
  }
}

// ---------------------------------------------------------------------------
// Edge pass 1: e = leaky_relu(el[src]+er[dst]); segment max over dst.
// emax zero-initialized == -inf under fenc ordering.
// ---------------------------------------------------------------------------
template<int H>
__global__ __launch_bounds__(256)
void edge_max(const int* __restrict__ src, const int* __restrict__ dst,
              const float* __restrict__ el, const float* __restrict__ er,
              float* __restrict__ ebuf, unsigned* __restrict__ emax, int E)
{
  int e = blockIdx.x * 256 + threadIdx.x;
  if (e >= E) return;
  int s = src[e], d = dst[e];
#pragma unroll
  for (int h = 0; h < H; ++h) {
    float v = el[s * H + h] + er[d * H + h];
    v = v > 0.f ? v : 0.2f * v;
    ebuf[e * H + h] = v;
    atomicMax(&emax[d * H + h], fenc(v));
  }
}

// Edge pass 2: ex = exp(e - max[dst]); segment-sum into denom.
template<int H>
__global__ __launch_bounds__(256)
void edge_expsum(const int* __restrict__ dst, float* __restrict__ ebuf,
                 const unsigned* __restrict__ emax, float* __restrict__ denom, int E)
{
  int e = blockIdx.x * 256 + threadIdx.x;
  if (e >= E) return;
  int d = dst[e];
#pragma unroll
  for (int h = 0; h < H; ++h) {
    float m = fdec(emax[d * H + h]);
    float x = expf(ebuf[e * H + h] - m);
    ebuf[e * H + h] = x;
    atomicAdd(&denom[d * H + h], x);
  }
}

// Edge pass 3: acc[dst] += (ex/denom[dst]) * zs[src]   (64 lanes per edge)
template<int H, int F>
__global__ __launch_bounds__(256)
void edge_msg(const int* __restrict__ src, const int* __restrict__ dst,
              const float* __restrict__ ebuf, const float* __restrict__ denom,
              const float* __restrict__ zs, float* __restrict__ acc, int E)
{
  constexpr int ELEMS = H * F;
  int t = blockIdx.x * 256 + threadIdx.x;
  int e = t >> 6;
  int lane = t & 63;
  if (e >= E) return;
  int s = src[e], d = dst[e];
#pragma unroll
  for (int x = lane; x < ELEMS; x += 64) {
    int h = x / F;
    float alpha = ebuf[e * H + h] / denom[d * H + h];
    atomicAdd(&acc[(size_t)d * ELEMS + x], alpha * zs[(size_t)s * ELEMS + x]);
  }
}

// acc[n, :] += b0 (+ b1) (+ b2)   — combined relation biases per dst type
__global__ __launch_bounds__(256)
void add_bias(float* __restrict__ acc,
              const float* __restrict__ b0,
              const float* __restrict__ b1p,
              const float* __restrict__ b2p,
              int N, int ELEMS)
{
  int t = blockIdx.x * 256 + threadIdx.x;
  if (t >= N * ELEMS) return;
  int x = t % ELEMS;
  float b = b0[x];
  if (b1p) b += b1p[x];
  if (b2p) b += b2p[x];
  acc[t] += b;
}

// Predictor: out[e] = dot64(h2a[src], h2t[dst]); pos edges then neg edges.
__global__ __launch_bounds__(256)
void pred_dot(const float* __restrict__ h2a, const float* __restrict__ h2t,
              const int* __restrict__ ps, const int* __restrict__ pd,
              const int* __restrict__ ns, const int* __restrict__ nd,
              float* __restrict__ out, int Ep, int En)
{
  int t = blockIdx.x * 256 + threadIdx.x;
  if (t >= Ep + En) return;
  int s, d;
  if (t < Ep) { s = ps[t]; d = pd[t]; }
  else        { s = ns[t - Ep]; d = nd[t - Ep]; }
  const float4* pa = (const float4*)(h2a + (size_t)s * 64);
  const float4* pb = (const float4*)(h2t + (size_t)d * 64);
  float acc = 0.f;
#pragma unroll
  for (int i = 0; i < 16; ++i) {
    float4 a = pa[i], b = pb[i];
    acc += a.x * b.x + a.y * b.y + a.z * b.z + a.w * b.w;
  }
  out[t] = acc;
}

// ---------------------------------------------------------------------------
extern "C" void kernel_launch(void* const* d_in, const int* in_sizes, int n_in,
                              void* d_out, int out_size, void* d_ws, size_t ws_size,
                              hipStream_t stream)
{
  (void)n_in; (void)out_size; (void)ws_size;
  const float* fUser = (const float*)d_in[0];
  const float* fArt  = (const float*)d_in[1];
  const float* fTag  = (const float*)d_in[2];
  const float* W1  = (const float*)d_in[3];
  const float* al1 = (const float*)d_in[4];
  const float* ar1 = (const float*)d_in[5];
  const float* b1  = (const float*)d_in[6];
  const float* W2  = (const float*)d_in[7];
  const float* al2 = (const float*)d_in[8];
  const float* ar2 = (const float*)d_in[9];
  const float* b2  = (const float*)d_in[10];
  const int* ix[14];
  for (int i = 0; i < 14; ++i) ix[i] = (const int*)d_in[11 + i];

  const int NU = in_sizes[0] / 128;
  const int NA = in_sizes[1] / 128;
  const int NT = in_sizes[2] / 128;
  const int E  = in_sizes[11];
  const int EN = in_sizes[23];

  char* p = (char*)d_ws;
  auto alloc = [&](size_t bytes) -> char* {
    char* r = p; p += (bytes + 255) & ~(size_t)255; return r;
  };

  // ---- zero-init region (one memset) ----
  char* zbase = p;
  const int dN1[6] = {NA, NU, NU, NU, NT, NA};
  unsigned* emax1[6]; float* den1[6];
  for (int r = 0; r < 6; ++r) emax1[r] = (unsigned*)alloc((size_t)dN1[r] * 4 * 4);
  for (int r = 0; r < 6; ++r) den1[r]  = (float*)alloc((size_t)dN1[r] * 4 * 4);
  const int dN2[3] = {NA, NA, NT};
  unsigned* emax2[3]; float* den2[3];
  for (int r = 0; r < 3; ++r) emax2[r] = (unsigned*)alloc((size_t)dN2[r] * 4);
  for (int r = 0; r < 3; ++r) den2[r]  = (float*)alloc((size_t)dN2[r] * 4);
  float* hU  = (float*)alloc((size_t)NU * 128 * 4);
  float* hA  = (float*)alloc((size_t)NA * 128 * 4);
  float* hT  = (float*)alloc((size_t)NT * 128 * 4);
  float* h2a = (float*)alloc((size_t)NA * 64 * 4);
  float* h2t = (float*)alloc((size_t)NT * 64 * 4);
  size_t zbytes = (size_t)(p - zbase);

  // ---- non-zero scratch ----
  const int sN1[6] = {NU, NA, NU, NU, NA, NT};
  const float* sF1[6] = {fUser, fArt, fUser, fUser, fArt, fTag};
  const float* dF1[6] = {fArt, fUser, fUser, fUser, fTag, fArt};
  float *zs1[6], *el1p[6], *er1p[6];
  for (int r = 0; r < 6; ++r) {
    zs1[r]  = (float*)alloc((size_t)sN1[r] * 128 * 4);   // src projections (stored)
    el1p[r] = (float*)alloc((size_t)sN1[r] * 4 * 4);
    er1p[r] = (float*)alloc((size_t)dN1[r] * 4 * 4);
  }
  const float* sF2[3]; const float* dF2[3];
  sF2[0] = hU; sF2[1] = hT; sF2[2] = hA;
  dF2[0] = hA; dF2[1] = hA; dF2[2] = hT;
  const int sN2[3] = {NU, NT, NA};
  const int W2i[3] = {0, 5, 4};
  float *zs2[3], *el2p[3], *er2p[3];
  for (int r = 0; r < 3; ++r) {
    zs2[r]  = (float*)alloc((size_t)sN2[r] * 64 * 4);
    el2p[r] = (float*)alloc((size_t)sN2[r] * 4);
    er2p[r] = (float*)alloc((size_t)dN2[r] * 4);
  }
  // single per-edge scratch, reused by every relation pass (sequential stream)
  float* eb = (float*)alloc((size_t)E * 4 * 4);

  hipMemsetAsync(zbase, 0, zbytes, stream);

  // ---- layer 1: projections + attention logits ----
  for (int r = 0; r < 6; ++r) {
    int nbs = (sN1[r] + 1) / 2;
    if (r == 2 || r == 3) {  // self-loop relation: one GEMM gives both dots
      gemm_attn<128, 128, 4><<<nbs, 256, 0, stream>>>(
          sF1[r], W1 + (size_t)r * 16384, zs1[r],
          el1p[r], al1 + r * 128, er1p[r], ar1 + r * 128, sN1[r]);
    } else {
      gemm_attn<128, 128, 4><<<nbs, 256, 0, stream>>>(
          sF1[r], W1 + (size_t)r * 16384, zs1[r],
          el1p[r], al1 + r * 128, nullptr, nullptr, sN1[r]);
      int nbd = (dN1[r] + 1) / 2;
      gemm_attn<128, 128, 4><<<nbd, 256, 0, stream>>>(   // er only, Z not stored
          dF1[r], W1 + (size_t)r * 16384, nullptr,
          nullptr, nullptr, er1p[r], ar1 + r * 128, dN1[r]);
    }
  }

  // ---- layer 1 edge phases ----
  float* acc1[6] = {hA, hU, hU, hU, hT, hA};
  const int ebks = (E + 255) / 256;
  const int mbks = (int)(((size_t)E * 64 + 255) / 256);
  for (int r = 0; r < 6; ++r) {
    const int* s = ix[2 * r]; const int* d = ix[2 * r + 1];
    edge_max<4><<<ebks, 256, 0, stream>>>(s, d, el1p[r], er1p[r], eb, emax1[r], E);
    edge_expsum<4><<<ebks, 256, 0, stream>>>(d, eb, emax1[r], den1[r], E);
    edge_msg<4, 32><<<mbks, 256, 0, stream>>>(s, d, eb, den1[r], zs1[r], acc1[r], E);
  }
  add_bias<<<(NU * 128 + 255) / 256, 256, 0, stream>>>(hU, b1 + 128, b1 + 2 * 128, b1 + 3 * 128, NU, 128);
  add_bias<<<(NA * 128 + 255) / 256, 256, 0, stream>>>(hA, b1, b1 + 5 * 128, nullptr, NA, 128);
  add_bias<<<(NT * 128 + 255) / 256, 256, 0, stream>>>(hT, b1 + 4 * 128, nullptr, nullptr, NT, 128);

  // ---- layer 2 (only relations feeding h2_artist / h2_tag) ----
  for (int r = 0; r < 3; ++r) {
    int w = W2i[r];
    int nbs = (sN2[r] + 3) / 4, nbd = (dN2[r] + 3) / 4;
    gemm_attn<128, 64, 1><<<nbs, 256, 0, stream>>>(
        sF2[r], W2 + (size_t)w * 8192, zs2[r],
        el2p[r], al2 + w * 64, nullptr, nullptr, sN2[r]);
    gemm_attn<128, 64, 1><<<nbd, 256, 0, stream>>>(
        dF2[r], W2 + (size_t)w * 8192, nullptr,
        nullptr, nullptr, er2p[r], ar2 + w * 64, dN2[r]);
  }
  const int* s2[3] = {ix[0], ix[10], ix[8]};
  const int* d2[3] = {ix[1], ix[11], ix[9]};
  float* acc2[3] = {h2a, h2a, h2t};
  for (int r = 0; r < 3; ++r) {
    edge_max<1><<<ebks, 256, 0, stream>>>(s2[r], d2[r], el2p[r], er2p[r], eb, emax2[r], E);
    edge_expsum<1><<<ebks, 256, 0, stream>>>(d2[r], eb, emax2[r], den2[r], E);
    edge_msg<1, 64><<<mbks, 256, 0, stream>>>(s2[r], d2[r], eb, den2[r], zs2[r], acc2[r], E);
  }
  add_bias<<<(NA * 64 + 255) / 256, 256, 0, stream>>>(h2a, b2, b2 + 5 * 64, nullptr, NA, 64);
  add_bias<<<(NT * 64 + 255) / 256, 256, 0, stream>>>(h2t, b2 + 4 * 64, nullptr, nullptr, NT, 64);

  // ---- predictor ----
  pred_dot<<<((E + EN) + 255) / 256, 256, 0, stream>>>(
      h2a, h2t, ix[8], ix[9], ix[12], ix[13], (float*)d_out, E, EN);
}

// Round 3
// 906.731 us; speedup vs baseline: 1.6011x; 1.6011x over previous
//
#include <hip/hip_runtime.h>

#define DEVI __device__ __forceinline__

// ---------------------------------------------------------------------------
// Register-tiled projection GEMM + fused attention-logit epilogue (all f32).
// Z[N,KOUT] = A[N,KIN] @ W[KIN,KOUT]          (Z optional)
// el[n,h]   = sum_f acc[n,h*F+f]*al[h*F+f]    (optional)
// er[n,h]   likewise with ar                  (optional)
// Block: 256 threads. G=256/KOUT row-groups, RPT rows/thread, TILE=G*RPT rows.
// A tile staged in LDS; per-k reads are wave-uniform broadcasts (conflict-free).
// ---------------------------------------------------------------------------
template<int KIN, int KOUT, int H, int RPT>
__global__ __launch_bounds__(256)
void gemm_attn(const float* __restrict__ A, const float* __restrict__ W,
               float* __restrict__ Z,
               float* __restrict__ el_out, const float* __restrict__ al,
               float* __restrict__ er_out, const float* __restrict__ ar,
               int N)
{
  constexpr int G = 256 / KOUT;
  constexpr int TILE = G * RPT;
  constexpr int F = KOUT / H;
  __shared__ float a_lds[TILE * KIN];
  const int row0 = blockIdx.x * TILE;
  for (int i = threadIdx.x; i < TILE * KIN; i += 256) {
    int rr = i / KIN;
    int row = row0 + rr;
    a_lds[i] = (row < N) ? A[(size_t)row * KIN + (i - rr * KIN)] : 0.f;
  }
  __syncthreads();
  const int c = threadIdx.x % KOUT;
  const int g = threadIdx.x / KOUT;
  const float* abase = a_lds + g * RPT * KIN;
  float acc[RPT];
#pragma unroll
  for (int j = 0; j < RPT; ++j) acc[j] = 0.f;
  for (int k4 = 0; k4 < KIN / 4; ++k4) {
    float w0 = W[(k4 * 4 + 0) * KOUT + c];
    float w1 = W[(k4 * 4 + 1) * KOUT + c];
    float w2 = W[(k4 * 4 + 2) * KOUT + c];
    float w3 = W[(k4 * 4 + 3) * KOUT + c];
#pragma unroll
    for (int j = 0; j < RPT; ++j) {
      float4 a4 = ((const float4*)(abase + j * KIN))[k4];  // wave-uniform broadcast
      acc[j] = fmaf(a4.x, w0, fmaf(a4.y, w1, fmaf(a4.z, w2, fmaf(a4.w, w3, acc[j]))));
    }
  }
  if (Z != nullptr) {
#pragma unroll
    for (int j = 0; j < RPT; ++j) {
      int row = row0 + g * RPT + j;
      if (row < N) Z[(size_t)row * KOUT + c] = acc[j];
    }
  }
  // attention dots: butterfly across the F lanes of each head group
  if (el_out != nullptr) {
#pragma unroll
    for (int j = 0; j < RPT; ++j) {
      float v = acc[j] * al[c];
#pragma unroll
      for (int m = 1; m < F; m <<= 1) v += __shfl_xor(v, m, 64);
      int row = row0 + g * RPT + j;
      if (row < N && (c & (F - 1)) == 0) el_out[row * H + (c / F)] = v;
    }
  }
  if (er_out != nullptr) {
#pragma unroll
    for (int j = 0; j < RPT; ++j) {
      float v = acc[j] * ar[c];
#pragma unroll
      for (int m = 1; m < F; m <<= 1) v += __shfl_xor(v, m, 64);
      int row = row0 + g * RPT + j;
      if (row < N && (c & (F - 1)) == 0) er_out[row * H + (c / F)] = v;
    }
  }
}

// ---------------------------------------------------------------------------
// Fused edge pass (the only per-edge kernel):
//   ex = exp(leaky_relu(el[src]+er[dst]))   (no max-subtraction: logits bounded)
//   denom[dst,h] += ex ;  acc[dst,:] += ex * zs[src,:]
// Normalization happens per-node in finalize. 64 lanes per edge.
// ---------------------------------------------------------------------------
template<int H, int F>
__global__ __launch_bounds__(256)
void edge_fused(const int* __restrict__ src, const int* __restrict__ dst,
                const float* __restrict__ el, const float* __restrict__ er,
                const float* __restrict__ zs,
                float* __restrict__ denom, float* __restrict__ acc, int E)
{
  constexpr int ELEMS = H * F;
  int t = blockIdx.x * 256 + threadIdx.x;
  int e = t >> 6, lane = t & 63;
  if (e >= E) return;
  int s = src[e], d = dst[e];
  float ex = 0.f;
  if (lane < H) {
    float v = el[s * H + lane] + er[d * H + lane];
    v = v > 0.f ? v : 0.2f * v;
    ex = __expf(v);
    atomicAdd(&denom[d * H + lane], ex);
  }
#pragma unroll
  for (int x0 = 0; x0 < ELEMS; x0 += 64) {
    int x = x0 + lane;
    float exh = __shfl(ex, x / F, 64);
    atomicAdd(&acc[(size_t)d * ELEMS + x], exh * zs[(size_t)s * ELEMS + x]);
  }
}

// ---------------------------------------------------------------------------
// finalize: out[n,x] = sum_r acc_r[n,x]/den_r[n,h] + sum_r b_r[x]
// (guards den==0 for isolated nodes; in-place onto acc0 is safe)
// ---------------------------------------------------------------------------
template<int ELEMS, int F, int H>
__global__ __launch_bounds__(256)
void finalize(float* __restrict__ out,
              const float* __restrict__ a0, const float* __restrict__ d0,
              const float* __restrict__ a1, const float* __restrict__ d1,
              const float* __restrict__ a2, const float* __restrict__ d2,
              const float* __restrict__ b0, const float* __restrict__ b1,
              const float* __restrict__ b2, int N)
{
  int t = blockIdx.x * 256 + threadIdx.x;
  if (t >= N * ELEMS) return;
  int x = t % ELEMS;
  int n = t / ELEMS;
  int h = x / F;
  float v = b0[x];
  if (b1) v += b1[x];
  if (b2) v += b2[x];
  float dd0 = d0[n * H + h];
  if (dd0 > 0.f) v += a0[t] / dd0;
  if (a1) { float dd = d1[n * H + h]; if (dd > 0.f) v += a1[t] / dd; }
  if (a2) { float dd = d2[n * H + h]; if (dd > 0.f) v += a2[t] / dd; }
  out[t] = v;
}

// ---------------------------------------------------------------------------
// Predictor: 16 lanes per edge, coalesced float4 row loads, shfl reduce.
// ---------------------------------------------------------------------------
__global__ __launch_bounds__(256)
void pred_dot(const float* __restrict__ h2a, const float* __restrict__ h2t,
              const int* __restrict__ ps, const int* __restrict__ pd,
              const int* __restrict__ ns, const int* __restrict__ nd,
              float* __restrict__ out, int Ep, int En)
{
  int t = blockIdx.x * 256 + threadIdx.x;
  int e = t >> 4, q = t & 15;
  if (e >= Ep + En) return;
  int s, d;
  if (e < Ep) { s = ps[e]; d = pd[e]; }
  else        { s = ns[e - Ep]; d = nd[e - Ep]; }
  float4 a = ((const float4*)(h2a + (size_t)s * 64))[q];
  float4 b = ((const float4*)(h2t + (size_t)d * 64))[q];
  float v = a.x * b.x + a.y * b.y + a.z * b.z + a.w * b.w;
  v += __shfl_xor(v, 8, 64);
  v += __shfl_xor(v, 4, 64);
  v += __shfl_xor(v, 2, 64);
  v += __shfl_xor(v, 1, 64);
  if (q == 0) out[e] = v;
}

// ---------------------------------------------------------------------------
extern "C" void kernel_launch(void* const* d_in, const int* in_sizes, int n_in,
                              void* d_out, int out_size, void* d_ws, size_t ws_size,
                              hipStream_t stream)
{
  (void)n_in; (void)out_size; (void)ws_size;
  const float* fUser = (const float*)d_in[0];
  const float* fArt  = (const float*)d_in[1];
  const float* fTag  = (const float*)d_in[2];
  const float* W1  = (const float*)d_in[3];
  const float* al1 = (const float*)d_in[4];
  const float* ar1 = (const float*)d_in[5];
  const float* b1  = (const float*)d_in[6];
  const float* W2  = (const float*)d_in[7];
  const float* al2 = (const float*)d_in[8];
  const float* ar2 = (const float*)d_in[9];
  const float* b2  = (const float*)d_in[10];
  const int* ix[14];
  for (int i = 0; i < 14; ++i) ix[i] = (const int*)d_in[11 + i];

  const int NU = in_sizes[0] / 128;
  const int NA = in_sizes[1] / 128;
  const int NT = in_sizes[2] / 128;
  const int E  = in_sizes[11];
  const int EN = in_sizes[23];

  char* p = (char*)d_ws;
  auto alloc = [&](size_t bytes) -> char* {
    char* r = p; p += (bytes + 255) & ~(size_t)255; return r;
  };

  const int dN1[6] = {NA, NU, NU, NU, NT, NA};
  const int sN1[6] = {NU, NA, NU, NU, NA, NT};
  const int dN2[3] = {NA, NA, NT};
  const int sN2[3] = {NU, NT, NA};

  // ---- zero-init region (one memset): denominators + accumulators ----
  char* zbase = p;
  float* den1[6]; float* den2[3]; float* acc1[6]; float* acc2[3];
  for (int r = 0; r < 6; ++r) den1[r] = (float*)alloc((size_t)dN1[r] * 4 * 4);
  for (int r = 0; r < 3; ++r) den2[r] = (float*)alloc((size_t)dN2[r] * 4);
  for (int r = 0; r < 6; ++r) acc1[r] = (float*)alloc((size_t)dN1[r] * 128 * 4);
  for (int r = 0; r < 3; ++r) acc2[r] = (float*)alloc((size_t)dN2[r] * 64 * 4);
  size_t zbytes = (size_t)(p - zbase);

  // ---- non-zero scratch ----
  float *zs1[6], *el1[6], *er1[6];
  for (int r = 0; r < 6; ++r) {
    zs1[r] = (float*)alloc((size_t)sN1[r] * 128 * 4);
    el1[r] = (float*)alloc((size_t)sN1[r] * 4 * 4);
    er1[r] = (float*)alloc((size_t)dN1[r] * 4 * 4);
  }
  float *el2[3], *er2[3];
  for (int r = 0; r < 3; ++r) {
    el2[r] = (float*)alloc((size_t)sN2[r] * 4);
    er2[r] = (float*)alloc((size_t)dN2[r] * 4);
  }
  // layer-2 src projections alias layer-1 zs (dead by then); sizes verified:
  // NU*64<=NU*128, NT*64<=NA*128, NA*64<=NU*128 (NA=2*NU)
  float* zs2[3] = {zs1[0], zs1[1], zs1[2]};

  // node feature buffers alias the first accumulator of each dst type
  float* hA  = acc1[0];
  float* hU  = acc1[1];
  float* hT  = acc1[4];
  float* h2a = acc2[0];
  float* h2t = acc2[2];

  hipMemsetAsync(zbase, 0, zbytes, stream);

  // ---- layer 1: projections + attention logits ----
  const float* sF1[6] = {fUser, fArt, fUser, fUser, fArt, fTag};
  const float* dF1[6] = {fArt, fUser, fUser, fUser, fTag, fArt};
  for (int r = 0; r < 6; ++r) {
    int nbs = (sN1[r] + 15) / 16;
    if (r == 2 || r == 3) {  // self-loop relation: one GEMM gives both dots
      gemm_attn<128, 128, 4, 8><<<nbs, 256, 0, stream>>>(
          sF1[r], W1 + (size_t)r * 16384, zs1[r],
          el1[r], al1 + r * 128, er1[r], ar1 + r * 128, sN1[r]);
    } else {
      gemm_attn<128, 128, 4, 8><<<nbs, 256, 0, stream>>>(
          sF1[r], W1 + (size_t)r * 16384, zs1[r],
          el1[r], al1 + r * 128, nullptr, nullptr, sN1[r]);
      int nbd = (dN1[r] + 15) / 16;
      gemm_attn<128, 128, 4, 8><<<nbd, 256, 0, stream>>>(  // er only, Z unstored
          dF1[r], W1 + (size_t)r * 16384, nullptr,
          nullptr, nullptr, er1[r], ar1 + r * 128, dN1[r]);
    }
  }

  // ---- layer 1: fused edge pass per relation ----
  const int ebks = (int)(((size_t)E * 64 + 255) / 256);
  for (int r = 0; r < 6; ++r) {
    edge_fused<4, 32><<<ebks, 256, 0, stream>>>(
        ix[2 * r], ix[2 * r + 1], el1[r], er1[r], zs1[r], den1[r], acc1[r], E);
  }

  // ---- layer 1 finalize (normalize + relation-sum + bias), in-place ----
  finalize<128, 32, 4><<<(NU * 128 + 255) / 256, 256, 0, stream>>>(
      hU, acc1[1], den1[1], acc1[2], den1[2], acc1[3], den1[3],
      b1 + 128, b1 + 256, b1 + 384, NU);
  finalize<128, 32, 4><<<(NA * 128 + 255) / 256, 256, 0, stream>>>(
      hA, acc1[0], den1[0], acc1[5], den1[5], nullptr, nullptr,
      b1, b1 + 5 * 128, nullptr, NA);
  finalize<128, 32, 4><<<(NT * 128 + 255) / 256, 256, 0, stream>>>(
      hT, acc1[4], den1[4], nullptr, nullptr, nullptr, nullptr,
      b1 + 4 * 128, nullptr, nullptr, NT);

  // ---- layer 2 (only relations feeding h2_artist / h2_tag) ----
  const float* sF2[3] = {hU, hT, hA};
  const float* dF2[3] = {hA, hA, hT};
  const int W2i[3] = {0, 5, 4};
  for (int r = 0; r < 3; ++r) {
    int w = W2i[r];
    int nbs = (sN2[r] + 31) / 32, nbd = (dN2[r] + 31) / 32;
    gemm_attn<128, 64, 1, 8><<<nbs, 256, 0, stream>>>(
        sF2[r], W2 + (size_t)w * 8192, zs2[r],
        el2[r], al2 + w * 64, nullptr, nullptr, sN2[r]);
    gemm_attn<128, 64, 1, 8><<<nbd, 256, 0, stream>>>(
        dF2[r], W2 + (size_t)w * 8192, nullptr,
        nullptr, nullptr, er2[r], ar2 + w * 64, dN2[r]);
  }
  const int* s2[3] = {ix[0], ix[10], ix[8]};
  const int* d2[3] = {ix[1], ix[11], ix[9]};
  for (int r = 0; r < 3; ++r) {
    edge_fused<1, 64><<<ebks, 256, 0, stream>>>(
        s2[r], d2[r], el2[r], er2[r], zs2[r], den2[r], acc2[r], E);
  }
  finalize<64, 64, 1><<<(NA * 64 + 255) / 256, 256, 0, stream>>>(
      h2a, acc2[0], den2[0], acc2[1], den2[1], nullptr, nullptr,
      b2, b2 + 5 * 64, nullptr, NA);
  finalize<64, 64, 1><<<(NT * 64 + 255) / 256, 256, 0, stream>>>(
      h2t, acc2[2], den2[2], nullptr, nullptr, nullptr, nullptr,
      b2 + 4 * 64, nullptr, nullptr, NT);

  // ---- predictor ----
  pred_dot<<<(int)(((size_t)(E + EN) * 16 + 255) / 256), 256, 0, stream>>>(
      h2a, h2t, ix[8], ix[9], ix[12], ix[13], (float*)d_out, E, EN);
}

// Round 4
// 547.916 us; speedup vs baseline: 2.6496x; 1.6549x over previous
//
#include <hip/hip_runtime.h>

// ---------------------------------------------------------------------------
// CSR build, batched over the 6 relations (all have exactly E edges).
// ---------------------------------------------------------------------------
struct CsrArgs {
  const int* src[6];
  const int* dst[6];
  int* cnt[6];
  int* offs[6];
  int* cur[6];
  int* csr[6];
  int  N[6];
};

__global__ __launch_bounds__(256)
void hist_all(CsrArgs a, int E, int ebks) {
  int r = blockIdx.x / ebks;
  int e = (blockIdx.x - r * ebks) * 256 + threadIdx.x;
  if (e >= E) return;
  atomicAdd(&a.cnt[r][a.dst[r][e]], 1);
}

__global__ __launch_bounds__(1024)
void scan_all(CsrArgs a) {
  __shared__ int psum[1024];
  int r = blockIdx.x;
  int N = a.N[r];
  const int* cnt = a.cnt[r];
  int* offs = a.offs[r];
  int t = threadIdx.x;
  int K = (N + 1023) / 1024;
  int i0 = t * K, i1 = min(i0 + K, N);
  int s = 0;
  for (int i = i0; i < i1; ++i) s += cnt[i];
  psum[t] = s;
  __syncthreads();
  for (int d = 1; d < 1024; d <<= 1) {
    int v = (t >= d) ? psum[t - d] : 0;
    __syncthreads();
    psum[t] += v;
    __syncthreads();
  }
  int run = (t == 0) ? 0 : psum[t - 1];
  for (int i = i0; i < i1; ++i) { offs[i] = run; run += cnt[i]; }
  if (t == 1023) offs[N] = run;   // t=1023 always has i1==N (K*1024 >= N)
}

__global__ __launch_bounds__(256)
void scatter_all(CsrArgs a, int E, int ebks) {
  int r = blockIdx.x / ebks;
  int e = (blockIdx.x - r * ebks) * 256 + threadIdx.x;
  if (e >= E) return;
  int d = a.dst[r][e];
  int pos = atomicAdd(&a.cur[r][d], 1);
  a.csr[r][a.offs[r][d] + pos] = a.src[r][e];
}

// ---------------------------------------------------------------------------
// prep: fold W@ar -> war per relation (so er = feat . war, no dst GEMM), and
// combine per-dsttype biases. Blocks 0-5: war1; 6-8: war2; 9: biases.
// ---------------------------------------------------------------------------
__global__ __launch_bounds__(256)
void prep(const float* __restrict__ W1, const float* __restrict__ ar1,
          const float* __restrict__ b1,
          const float* __restrict__ W2, const float* __restrict__ ar2,
          const float* __restrict__ b2,
          float* __restrict__ war1, float* __restrict__ war2,
          float* __restrict__ bcomb)  // [bU 128 | bA 128 | bT 128 | b2a 64 | b2t 64]
{
  int b = blockIdx.x, t = threadIdx.x;
  if (b < 6) {
    for (int i = t; i < 512; i += 256) {
      int k = i >> 2, h = i & 3;
      float s = 0.f;
      for (int f = 0; f < 32; ++f)
        s += W1[b * 16384 + k * 128 + h * 32 + f] * ar1[b * 128 + h * 32 + f];
      war1[b * 512 + k * 4 + h] = s;
    }
  } else if (b < 9) {
    int w = (b == 6) ? 0 : (b == 7) ? 5 : 4;
    if (t < 128) {
      float s = 0.f;
      for (int f = 0; f < 64; ++f)
        s += W2[w * 8192 + t * 64 + f] * ar2[w * 64 + f];
      war2[(b - 6) * 128 + t] = s;
    }
  } else {
    if (t < 128) {
      bcomb[t]       = b1[128 + t] + b1[256 + t] + b1[384 + t]; // user
      bcomb[128 + t] = b1[t] + b1[640 + t];                     // artist
      bcomb[256 + t] = b1[512 + t];                             // tag
    } else if (t < 192) {
      int x = t - 128;
      bcomb[384 + x] = b2[x] + b2[320 + x];                     // h2 artist
      bcomb[448 + x] = b2[256 + x];                             // h2 tag
    }
  }
}

// ---------------------------------------------------------------------------
// Register-tiled projection GEMM + fused el epilogue (src side only now).
// ---------------------------------------------------------------------------
template<int KIN, int KOUT, int H, int RPT>
__global__ __launch_bounds__(256)
void gemm_attn(const float* __restrict__ A, const float* __restrict__ W,
               float* __restrict__ Z,
               float* __restrict__ el_out, const float* __restrict__ al,
               int N)
{
  constexpr int G = 256 / KOUT;
  constexpr int TILE = G * RPT;
  constexpr int F = KOUT / H;
  __shared__ float a_lds[TILE * KIN];
  const int row0 = blockIdx.x * TILE;
  for (int i = threadIdx.x; i < TILE * KIN; i += 256) {
    int rr = i / KIN;
    int row = row0 + rr;
    a_lds[i] = (row < N) ? A[(size_t)row * KIN + (i - rr * KIN)] : 0.f;
  }
  __syncthreads();
  const int c = threadIdx.x % KOUT;
  const int g = threadIdx.x / KOUT;
  const float* abase = a_lds + g * RPT * KIN;
  float acc[RPT];
#pragma unroll
  for (int j = 0; j < RPT; ++j) acc[j] = 0.f;
  for (int k4 = 0; k4 < KIN / 4; ++k4) {
    float w0 = W[(k4 * 4 + 0) * KOUT + c];
    float w1 = W[(k4 * 4 + 1) * KOUT + c];
    float w2 = W[(k4 * 4 + 2) * KOUT + c];
    float w3 = W[(k4 * 4 + 3) * KOUT + c];
#pragma unroll
    for (int j = 0; j < RPT; ++j) {
      float4 a4 = ((const float4*)(abase + j * KIN))[k4];  // wave-uniform broadcast
      acc[j] = fmaf(a4.x, w0, fmaf(a4.y, w1, fmaf(a4.z, w2, fmaf(a4.w, w3, acc[j]))));
    }
  }
#pragma unroll
  for (int j = 0; j < RPT; ++j) {
    int row = row0 + g * RPT + j;
    if (row < N) Z[(size_t)row * KOUT + c] = acc[j];
  }
#pragma unroll
  for (int j = 0; j < RPT; ++j) {
    float v = acc[j] * al[c];
#pragma unroll
    for (int m = 1; m < F; m <<= 1) v += __shfl_xor(v, m, 64);
    int row = row0 + g * RPT + j;
    if (row < N && (c & (F - 1)) == 0) el_out[row * H + (c / F)] = v;
  }
}

// ---------------------------------------------------------------------------
// CSR aggregation: one wave per dst node. Computes er in-wave from war,
// walks the node's edge segment, accumulates Sum(ex*zs[src]) and Sum(ex) in
// registers, writes out = (bias | out) + acc/den once. No atomics.
// H=4,CPL=2 -> ELEMS=128 (layer 1); H=1,CPL=1 -> ELEMS=64 (layer 2).
// ---------------------------------------------------------------------------
template<int H, int CPL, bool INIT>
__global__ __launch_bounds__(256)
void agg_csr(const int* __restrict__ offs, const int* __restrict__ csr,
             const float* __restrict__ el, const float* __restrict__ zs,
             const float* __restrict__ dfeat, const float* __restrict__ war,
             const float* __restrict__ bias, float* __restrict__ out, int Nd)
{
  constexpr int ELEMS = 64 * CPL;
  constexpr int F = ELEMS / H;
  __shared__ float war_s[128 * H];
  for (int i = threadIdx.x; i < 128 * H; i += 256) war_s[i] = war[i];
  __syncthreads();
  const int lane = threadIdx.x & 63;
  const int n = blockIdx.x * 4 + (threadIdx.x >> 6);
  if (n >= Nd) return;   // whole wave exits together
  // er[h] = dot(dfeat[n,:128], war[:,h]) — full-wave butterfly
  float2 f2 = ((const float2*)(dfeat + (size_t)n * 128))[lane];
  float er[H];
#pragma unroll
  for (int h = 0; h < H; ++h) {
    float v = f2.x * war_s[(2 * lane) * H + h] + f2.y * war_s[(2 * lane + 1) * H + h];
#pragma unroll
    for (int m = 1; m < 64; m <<= 1) v += __shfl_xor(v, m, 64);
    er[h] = v;
  }
  // static select (avoid dynamic register indexing -> scratch)
  float erl = er[0];
#pragma unroll
  for (int h = 1; h < H; ++h) erl = (lane == h) ? er[h] : erl;

  float acc[CPL];
#pragma unroll
  for (int j = 0; j < CPL; ++j) acc[j] = 0.f;
  float den = 0.f;                       // lanes 0..H-1 hold den[lane]
  const int hlane = (CPL * lane) / F;    // head of this lane's columns
  const int e0 = offs[n], e1 = offs[n + 1];
  for (int eb = e0; eb < e1; eb += 64) {
    int sv = (eb + lane < e1) ? csr[eb + lane] : 0;
    int m = min(64, e1 - eb);
    for (int j = 0; j < m; ++j) {
      int s = __shfl(sv, j, 64);
      float ex = 0.f;
      if (lane < H) {
        float v = el[s * H + lane] + erl;
        v = v > 0.f ? v : 0.2f * v;
        ex = __expf(v);
        den += ex;
      }
      float exh = __shfl(ex, hlane, 64);
      const float* zrow = zs + (size_t)s * ELEMS;
      if (CPL == 2) {
        float2 z2 = ((const float2*)zrow)[lane];
        acc[0] += exh * z2.x;
        acc[1] += exh * z2.y;
      } else {
        acc[0] += exh * zrow[lane];
      }
    }
  }
#pragma unroll
  for (int j = 0; j < CPL; ++j) {
    int x = CPL * lane + j;
    float dd = __shfl(den, x / F, 64);
    float v = INIT ? bias[x] : out[(size_t)n * ELEMS + x];
    if (dd > 0.f) v += acc[j] / dd;
    out[(size_t)n * ELEMS + x] = v;
  }
}

// ---------------------------------------------------------------------------
// Predictor: 16 lanes per edge, coalesced float4 row loads, shfl reduce.
// ---------------------------------------------------------------------------
__global__ __launch_bounds__(256)
void pred_dot(const float* __restrict__ h2a, const float* __restrict__ h2t,
              const int* __restrict__ ps, const int* __restrict__ pd,
              const int* __restrict__ ns, const int* __restrict__ nd,
              float* __restrict__ out, int Ep, int En)
{
  int t = blockIdx.x * 256 + threadIdx.x;
  int e = t >> 4, q = t & 15;
  if (e >= Ep + En) return;
  int s, d;
  if (e < Ep) { s = ps[e]; d = pd[e]; }
  else        { s = ns[e - Ep]; d = nd[e - Ep]; }
  float4 a = ((const float4*)(h2a + (size_t)s * 64))[q];
  float4 b = ((const float4*)(h2t + (size_t)d * 64))[q];
  float v = a.x * b.x + a.y * b.y + a.z * b.z + a.w * b.w;
  v += __shfl_xor(v, 8, 64);
  v += __shfl_xor(v, 4, 64);
  v += __shfl_xor(v, 2, 64);
  v += __shfl_xor(v, 1, 64);
  if (q == 0) out[e] = v;
}

// ---------------------------------------------------------------------------
extern "C" void kernel_launch(void* const* d_in, const int* in_sizes, int n_in,
                              void* d_out, int out_size, void* d_ws, size_t ws_size,
                              hipStream_t stream)
{
  (void)n_in; (void)out_size; (void)ws_size;
  const float* fUser = (const float*)d_in[0];
  const float* fArt  = (const float*)d_in[1];
  const float* fTag  = (const float*)d_in[2];
  const float* W1  = (const float*)d_in[3];
  const float* al1 = (const float*)d_in[4];
  const float* ar1 = (const float*)d_in[5];
  const float* b1  = (const float*)d_in[6];
  const float* W2  = (const float*)d_in[7];
  const float* al2 = (const float*)d_in[8];
  const float* ar2 = (const float*)d_in[9];
  const float* b2  = (const float*)d_in[10];
  const int* ix[14];
  for (int i = 0; i < 14; ++i) ix[i] = (const int*)d_in[11 + i];

  const int NU = in_sizes[0] / 128;
  const int NA = in_sizes[1] / 128;
  const int NT = in_sizes[2] / 128;
  const int E  = in_sizes[11];
  const int EN = in_sizes[23];

  char* p = (char*)d_ws;
  auto alloc = [&](size_t bytes) -> char* {
    char* r = p; p += (bytes + 255) & ~(size_t)255; return r;
  };

  const int dN1[6] = {NA, NU, NU, NU, NT, NA};
  const int sN1[6] = {NU, NA, NU, NU, NA, NT};
  const int sN2[3] = {NU, NT, NA};

  // ---- zero-init region: CSR counters + cursors ----
  char* zbase = p;
  CsrArgs ca;
  for (int r = 0; r < 6; ++r) ca.cnt[r] = (int*)alloc((size_t)dN1[r] * 4);
  for (int r = 0; r < 6; ++r) ca.cur[r] = (int*)alloc((size_t)dN1[r] * 4);
  size_t zbytes = (size_t)(p - zbase);

  // ---- non-zero scratch ----
  int* offs[6]; int* csr[6];
  for (int r = 0; r < 6; ++r) {
    offs[r] = (int*)alloc(((size_t)dN1[r] + 1) * 4);
    csr[r]  = (int*)alloc((size_t)E * 4);
    ca.src[r] = ix[2 * r]; ca.dst[r] = ix[2 * r + 1];
    ca.offs[r] = offs[r]; ca.csr[r] = csr[r]; ca.N[r] = dN1[r];
  }
  float* war1  = (float*)alloc(6 * 512 * 4);
  float* war2  = (float*)alloc(3 * 128 * 4);
  float* bcomb = (float*)alloc(512 * 4);
  float *zs1[6], *el1[6];
  for (int r = 0; r < 6; ++r) {
    zs1[r] = (float*)alloc((size_t)sN1[r] * 128 * 4);
    el1[r] = (float*)alloc((size_t)sN1[r] * 4 * 4);
  }
  float* hU  = (float*)alloc((size_t)NU * 128 * 4);
  float* hA  = (float*)alloc((size_t)NA * 128 * 4);
  float* hT  = (float*)alloc((size_t)NT * 128 * 4);
  float *zs2[3], *el2[3];
  for (int r = 0; r < 3; ++r) {
    zs2[r] = (float*)alloc((size_t)sN2[r] * 64 * 4);
    el2[r] = (float*)alloc((size_t)sN2[r] * 4);
  }
  float* h2a = (float*)alloc((size_t)NA * 64 * 4);
  float* h2t = (float*)alloc((size_t)NT * 64 * 4);

  hipMemsetAsync(zbase, 0, zbytes, stream);

  // ---- prep (war folding + combined biases) & CSR build ----
  prep<<<10, 256, 0, stream>>>(W1, ar1, b1, W2, ar2, b2, war1, war2, bcomb);
  const int EB = (E + 255) / 256;
  hist_all<<<6 * EB, 256, 0, stream>>>(ca, E, EB);
  scan_all<<<6, 1024, 0, stream>>>(ca);
  scatter_all<<<6 * EB, 256, 0, stream>>>(ca, E, EB);

  // ---- layer 1: src projections (Z + el) ----
  const float* sF1[6] = {fUser, fArt, fUser, fUser, fArt, fTag};
  for (int r = 0; r < 6; ++r) {
    gemm_attn<128, 128, 4, 8><<<(sN1[r] + 15) / 16, 256, 0, stream>>>(
        sF1[r], W1 + (size_t)r * 16384, zs1[r], el1[r], al1 + r * 128, sN1[r]);
  }

  // ---- layer 1: CSR aggregation (INIT seeds combined bias) ----
  agg_csr<4, 2, true ><<<(NA + 3) / 4, 256, 0, stream>>>(
      offs[0], csr[0], el1[0], zs1[0], fArt, war1 + 0 * 512, bcomb + 128, hA, NA);
  agg_csr<4, 2, false><<<(NA + 3) / 4, 256, 0, stream>>>(
      offs[5], csr[5], el1[5], zs1[5], fArt, war1 + 5 * 512, nullptr, hA, NA);
  agg_csr<4, 2, true ><<<(NU + 3) / 4, 256, 0, stream>>>(
      offs[1], csr[1], el1[1], zs1[1], fUser, war1 + 1 * 512, bcomb, hU, NU);
  agg_csr<4, 2, false><<<(NU + 3) / 4, 256, 0, stream>>>(
      offs[2], csr[2], el1[2], zs1[2], fUser, war1 + 2 * 512, nullptr, hU, NU);
  agg_csr<4, 2, false><<<(NU + 3) / 4, 256, 0, stream>>>(
      offs[3], csr[3], el1[3], zs1[3], fUser, war1 + 3 * 512, nullptr, hU, NU);
  agg_csr<4, 2, true ><<<(NT + 3) / 4, 256, 0, stream>>>(
      offs[4], csr[4], el1[4], zs1[4], fTag, war1 + 4 * 512, bcomb + 256, hT, NT);

  // ---- layer 2: src projections ----
  const float* sF2[3] = {hU, hT, hA};
  const int W2i[3] = {0, 5, 4};
  for (int r = 0; r < 3; ++r) {
    int w = W2i[r];
    gemm_attn<128, 64, 1, 8><<<(sN2[r] + 31) / 32, 256, 0, stream>>>(
        sF2[r], W2 + (size_t)w * 8192, zs2[r], el2[r], al2 + w * 64, sN2[r]);
  }

  // ---- layer 2: CSR aggregation (reuses CSRs 0/5/4) ----
  agg_csr<1, 1, true ><<<(NA + 3) / 4, 256, 0, stream>>>(
      offs[0], csr[0], el2[0], zs2[0], hA, war2 + 0 * 128, bcomb + 384, h2a, NA);
  agg_csr<1, 1, false><<<(NA + 3) / 4, 256, 0, stream>>>(
      offs[5], csr[5], el2[1], zs2[1], hA, war2 + 1 * 128, nullptr, h2a, NA);
  agg_csr<1, 1, true ><<<(NT + 3) / 4, 256, 0, stream>>>(
      offs[4], csr[4], el2[2], zs2[2], hT, war2 + 2 * 128, bcomb + 448, h2t, NT);

  // ---- predictor ----
  pred_dot<<<(int)(((size_t)(E + EN) * 16 + 255) / 256), 256, 0, stream>>>(
      h2a, h2t, ix[8], ix[9], ix[12], ix[13], (float*)d_out, E, EN);
}

// Round 5
// 400.443 us; speedup vs baseline: 3.6254x; 1.3683x over previous
//
#include <hip/hip_runtime.h>
#include <hip/hip_bf16.h>

#define DEVI __device__ __forceinline__

DEVI float blo(unsigned u){ return __uint_as_float(u << 16); }
DEVI float bhi(unsigned u){ return __uint_as_float(u & 0xffff0000u); }

// ---------------------------------------------------------------------------
// CSR build, batched over the 6 relations (all have exactly E edges).
// 4 edges per thread (stride 256) for memory-level parallelism.
// ---------------------------------------------------------------------------
struct CsrArgs {
  const int* src[6];
  const int* dst[6];
  int* cnt[6];
  int* offs[6];
  int* cur[6];
  int* csr[6];
  int  N[6];
};

__global__ __launch_bounds__(256)
void hist_all(CsrArgs a, int E, int ebks) {
  int r = blockIdx.x / ebks;
  int base = (blockIdx.x - r * ebks) * 1024 + threadIdx.x;
  const int* dst = a.dst[r];
  int* cnt = a.cnt[r];
#pragma unroll
  for (int k = 0; k < 4; ++k) {
    int e = base + k * 256;
    if (e < E) atomicAdd(&cnt[dst[e]], 1);
  }
}

__global__ __launch_bounds__(1024)
void scan_all(CsrArgs a) {
  __shared__ int psum[1024];
  int r = blockIdx.x;
  int N = a.N[r];
  const int* cnt = a.cnt[r];
  int* offs = a.offs[r];
  int t = threadIdx.x;
  int K = (N + 1023) / 1024;
  int i0 = t * K, i1 = min(i0 + K, N);
  int s = 0;
  for (int i = i0; i < i1; ++i) s += cnt[i];
  psum[t] = s;
  __syncthreads();
  for (int d = 1; d < 1024; d <<= 1) {
    int v = (t >= d) ? psum[t - d] : 0;
    __syncthreads();
    psum[t] += v;
    __syncthreads();
  }
  int run = (t == 0) ? 0 : psum[t - 1];
  for (int i = i0; i < i1; ++i) { offs[i] = run; run += cnt[i]; }
  if (t == 1023) offs[N] = run;   // t=1023 always has i1==N (K*1024 >= N)
}

__global__ __launch_bounds__(256)
void scatter_all(CsrArgs a, int E, int ebks) {
  int r = blockIdx.x / ebks;
  int base = (blockIdx.x - r * ebks) * 1024 + threadIdx.x;
  const int* dst = a.dst[r];
  const int* src = a.src[r];
  const int* offs = a.offs[r];
  int* cur = a.cur[r];
  int* csr = a.csr[r];
#pragma unroll
  for (int k = 0; k < 4; ++k) {
    int e = base + k * 256;
    if (e < E) {
      int d = dst[e];
      int pos = atomicAdd(&cur[d], 1);
      csr[offs[d] + pos] = src[e];
    }
  }
}

// ---------------------------------------------------------------------------
// prep: fold W@ar -> war per relation (er = feat . war, no dst GEMM), and
// combine per-dsttype biases. Blocks 0-5: war1; 6-8: war2; 9: biases.
// ---------------------------------------------------------------------------
__global__ __launch_bounds__(256)
void prep(const float* __restrict__ W1, const float* __restrict__ ar1,
          const float* __restrict__ b1,
          const float* __restrict__ W2, const float* __restrict__ ar2,
          const float* __restrict__ b2,
          float* __restrict__ war1, float* __restrict__ war2,
          float* __restrict__ bcomb)  // [bU 128 | bA 128 | bT 128 | b2a 64 | b2t 64]
{
  int b = blockIdx.x, t = threadIdx.x;
  if (b < 6) {
    for (int i = t; i < 512; i += 256) {
      int k = i >> 2, h = i & 3;
      float s = 0.f;
      for (int f = 0; f < 32; ++f)
        s += W1[b * 16384 + k * 128 + h * 32 + f] * ar1[b * 128 + h * 32 + f];
      war1[b * 512 + k * 4 + h] = s;
    }
  } else if (b < 9) {
    int w = (b == 6) ? 0 : (b == 7) ? 5 : 4;
    if (t < 128) {
      float s = 0.f;
      for (int f = 0; f < 64; ++f)
        s += W2[w * 8192 + t * 64 + f] * ar2[w * 64 + f];
      war2[(b - 6) * 128 + t] = s;
    }
  } else {
    if (t < 128) {
      bcomb[t]       = b1[128 + t] + b1[256 + t] + b1[384 + t]; // user
      bcomb[128 + t] = b1[t] + b1[640 + t];                     // artist
      bcomb[256 + t] = b1[512 + t];                             // tag
    } else if (t < 192) {
      int x = t - 128;
      bcomb[384 + x] = b2[x] + b2[320 + x];                     // h2 artist
      bcomb[448 + x] = b2[256 + x];                             // h2 tag
    }
  }
}

// ---------------------------------------------------------------------------
// Batched register-tiled projection GEMM + fused el epilogue.
// One launch covers all relations; block -> relation via pre[] prefix.
// Z stored bf16 (gathered later); el f32.
// ---------------------------------------------------------------------------
struct GemmB {
  const float* A[6];
  const float* W[6];
  const float* al[6];
  __hip_bfloat16* Z[6];
  float* el[6];
  int N[6];
  int pre[6];
};

template<int KIN, int KOUT, int H, int RPT>
__global__ __launch_bounds__(256)
void gemm_batch(GemmB g)
{
  constexpr int G = 256 / KOUT;
  constexpr int TILE = G * RPT;
  constexpr int F = KOUT / H;
  int r = 0;
#pragma unroll
  for (int i = 1; i < 6; ++i) if ((int)blockIdx.x >= g.pre[i]) r = i;
  const float* A = g.A[r];
  const float* W = g.W[r];
  const float* al = g.al[r];
  __hip_bfloat16* Z = g.Z[r];
  float* el_out = g.el[r];
  const int N = g.N[r];
  const int row0 = (blockIdx.x - g.pre[r]) * TILE;

  __shared__ float a_lds[TILE * KIN];
  for (int i = threadIdx.x; i < TILE * KIN; i += 256) {
    int rr = i / KIN;
    int row = row0 + rr;
    a_lds[i] = (row < N) ? A[(size_t)row * KIN + (i - rr * KIN)] : 0.f;
  }
  __syncthreads();
  const int c = threadIdx.x % KOUT;
  const int rg = threadIdx.x / KOUT;
  const float* abase = a_lds + rg * RPT * KIN;
  float acc[RPT];
#pragma unroll
  for (int j = 0; j < RPT; ++j) acc[j] = 0.f;
  for (int k4 = 0; k4 < KIN / 4; ++k4) {
    float w0 = W[(k4 * 4 + 0) * KOUT + c];
    float w1 = W[(k4 * 4 + 1) * KOUT + c];
    float w2 = W[(k4 * 4 + 2) * KOUT + c];
    float w3 = W[(k4 * 4 + 3) * KOUT + c];
#pragma unroll
    for (int j = 0; j < RPT; ++j) {
      float4 a4 = ((const float4*)(abase + j * KIN))[k4];  // wave-uniform broadcast
      acc[j] = fmaf(a4.x, w0, fmaf(a4.y, w1, fmaf(a4.z, w2, fmaf(a4.w, w3, acc[j]))));
    }
  }
#pragma unroll
  for (int j = 0; j < RPT; ++j) {
    int row = row0 + rg * RPT + j;
    if (row < N) Z[(size_t)row * KOUT + c] = __float2bfloat16(acc[j]);
  }
#pragma unroll
  for (int j = 0; j < RPT; ++j) {
    float v = acc[j] * al[c];
#pragma unroll
    for (int m = 1; m < F; m <<= 1) v += __shfl_xor(v, m, 64);
    int row = row0 + rg * RPT + j;
    if (row < N && (c & (F - 1)) == 0) el_out[row * H + (c / F)] = v;
  }
}

// ---------------------------------------------------------------------------
// Fused multi-relation CSR aggregation: one wave per dst node; walks each
// relation's segment sequentially (registers reused), writes out ONCE.
// er computed in-wave from war (folded W@ar). bf16 zs gathers. No atomics.
// ---------------------------------------------------------------------------
struct AggP {
  const int* offs[3];
  const int* csr[3];
  const float* el[3];
  const __hip_bfloat16* zs[3];
  const float* war[3];
  const float* bias;
  const float* dfeat;
  float* out;
  int Nd;
};

template<int H, int CPL, int NR>
__global__ __launch_bounds__(256)
void agg_multi(AggP a)
{
  constexpr int ELEMS = 64 * CPL;
  constexpr int F = ELEMS / H;
  __shared__ float war_s[NR * 128 * H];
  for (int i = threadIdx.x; i < NR * 128 * H; i += 256) {
    int rr = i / (128 * H);
    war_s[i] = a.war[rr][i - rr * 128 * H];
  }
  __syncthreads();
  const int lane = threadIdx.x & 63;
  const int n = blockIdx.x * 4 + (threadIdx.x >> 6);
  if (n >= a.Nd) return;   // whole wave exits together

  float2 f2 = ((const float2*)(a.dfeat + (size_t)n * 128))[lane];
  const int hlane = (CPL * lane) / F;   // head owning this lane's columns
  float vout[CPL];
#pragma unroll
  for (int j = 0; j < CPL; ++j) vout[j] = a.bias[CPL * lane + j];

#pragma unroll
  for (int r = 0; r < NR; ++r) {
    // er[h] = dot(dfeat[n,:], war_r[:,h]) — full-wave butterflies
    const float* ws = war_s + r * 128 * H;
    float er[H];
#pragma unroll
    for (int h = 0; h < H; ++h) {
      float v = f2.x * ws[(2 * lane) * H + h] + f2.y * ws[(2 * lane + 1) * H + h];
#pragma unroll
      for (int m = 1; m < 64; m <<= 1) v += __shfl_xor(v, m, 64);
      er[h] = v;
    }
    float erl = er[0];   // static select: lane h holds er[h]
#pragma unroll
    for (int h = 1; h < H; ++h) erl = (lane == h) ? er[h] : erl;

    const float* el = a.el[r];
    const int* csr = a.csr[r];
    float accA[CPL], accB[CPL];
#pragma unroll
    for (int j = 0; j < CPL; ++j) { accA[j] = 0.f; accB[j] = 0.f; }
    float denA = 0.f, denB = 0.f;   // lanes 0..H-1 hold per-head partials
    const int e0 = a.offs[r][n], e1 = a.offs[r][n + 1];
    for (int eb = e0; eb < e1; eb += 64) {
      int sv = (eb + lane < e1) ? csr[eb + lane] : 0;
      int m = min(64, e1 - eb);
      int j = 0;
      for (; j + 2 <= m; j += 2) {       // 2-way ILP: dual accumulators
        int s0 = __shfl(sv, j, 64), s1 = __shfl(sv, j + 1, 64);
        float ex0 = 0.f, ex1 = 0.f;
        if (lane < H) {
          float v0 = el[s0 * H + lane] + erl;
          v0 = v0 > 0.f ? v0 : 0.2f * v0;
          ex0 = __expf(v0); denA += ex0;
          float v1 = el[s1 * H + lane] + erl;
          v1 = v1 > 0.f ? v1 : 0.2f * v1;
          ex1 = __expf(v1); denB += ex1;
        }
        float eh0 = __shfl(ex0, hlane, 64);
        float eh1 = __shfl(ex1, hlane, 64);
        if (CPL == 2) {
          unsigned z0 = ((const unsigned*)a.zs[r])[(size_t)s0 * (ELEMS / 2) + lane];
          unsigned z1 = ((const unsigned*)a.zs[r])[(size_t)s1 * (ELEMS / 2) + lane];
          accA[0] += eh0 * blo(z0); accA[CPL - 1] += eh0 * bhi(z0);
          accB[0] += eh1 * blo(z1); accB[CPL - 1] += eh1 * bhi(z1);
        } else {
          unsigned z0 = ((const unsigned short*)a.zs[r])[(size_t)s0 * ELEMS + lane];
          unsigned z1 = ((const unsigned short*)a.zs[r])[(size_t)s1 * ELEMS + lane];
          accA[0] += eh0 * blo(z0 << 0);
          accB[0] += eh1 * blo(z1 << 0);
        }
      }
      for (; j < m; ++j) {
        int s0 = __shfl(sv, j, 64);
        float ex0 = 0.f;
        if (lane < H) {
          float v0 = el[s0 * H + lane] + erl;
          v0 = v0 > 0.f ? v0 : 0.2f * v0;
          ex0 = __expf(v0); denA += ex0;
        }
        float eh0 = __shfl(ex0, hlane, 64);
        if (CPL == 2) {
          unsigned z0 = ((const unsigned*)a.zs[r])[(size_t)s0 * (ELEMS / 2) + lane];
          accA[0] += eh0 * blo(z0); accA[CPL - 1] += eh0 * bhi(z0);
        } else {
          unsigned z0 = ((const unsigned short*)a.zs[r])[(size_t)s0 * ELEMS + lane];
          accA[0] += eh0 * blo(z0 << 0);
        }
      }
    }
#pragma unroll
    for (int j = 0; j < CPL; ++j) {
      int x = CPL * lane + j;
      float dd = __shfl(denA + denB, x / F, 64);
      if (dd > 0.f) vout[j] += (accA[j] + accB[j]) / dd;
    }
  }
  if (CPL == 2) {
    float2 o; o.x = vout[0]; o.y = vout[CPL - 1];
    ((float2*)(a.out + (size_t)n * ELEMS))[lane] = o;
  } else {
    a.out[(size_t)n * ELEMS + lane] = vout[0];
  }
}

// ---------------------------------------------------------------------------
// Predictor: 16 lanes per edge, coalesced float4 row loads, shfl reduce.
// ---------------------------------------------------------------------------
__global__ __launch_bounds__(256)
void pred_dot(const float* __restrict__ h2a, const float* __restrict__ h2t,
              const int* __restrict__ ps, const int* __restrict__ pd,
              const int* __restrict__ ns, const int* __restrict__ nd,
              float* __restrict__ out, int Ep, int En)
{
  int t = blockIdx.x * 256 + threadIdx.x;
  int e = t >> 4, q = t & 15;
  if (e >= Ep + En) return;
  int s, d;
  if (e < Ep) { s = ps[e]; d = pd[e]; }
  else        { s = ns[e - Ep]; d = nd[e - Ep]; }
  float4 a = ((const float4*)(h2a + (size_t)s * 64))[q];
  float4 b = ((const float4*)(h2t + (size_t)d * 64))[q];
  float v = a.x * b.x + a.y * b.y + a.z * b.z + a.w * b.w;
  v += __shfl_xor(v, 8, 64);
  v += __shfl_xor(v, 4, 64);
  v += __shfl_xor(v, 2, 64);
  v += __shfl_xor(v, 1, 64);
  if (q == 0) out[e] = v;
}

// ---------------------------------------------------------------------------
extern "C" void kernel_launch(void* const* d_in, const int* in_sizes, int n_in,
                              void* d_out, int out_size, void* d_ws, size_t ws_size,
                              hipStream_t stream)
{
  (void)n_in; (void)out_size; (void)ws_size;
  const float* fUser = (const float*)d_in[0];
  const float* fArt  = (const float*)d_in[1];
  const float* fTag  = (const float*)d_in[2];
  const float* W1  = (const float*)d_in[3];
  const float* al1 = (const float*)d_in[4];
  const float* ar1 = (const float*)d_in[5];
  const float* b1  = (const float*)d_in[6];
  const float* W2  = (const float*)d_in[7];
  const float* al2 = (const float*)d_in[8];
  const float* ar2 = (const float*)d_in[9];
  const float* b2  = (const float*)d_in[10];
  const int* ix[14];
  for (int i = 0; i < 14; ++i) ix[i] = (const int*)d_in[11 + i];

  const int NU = in_sizes[0] / 128;
  const int NA = in_sizes[1] / 128;
  const int NT = in_sizes[2] / 128;
  const int E  = in_sizes[11];
  const int EN = in_sizes[23];

  char* p = (char*)d_ws;
  auto alloc = [&](size_t bytes) -> char* {
    char* r = p; p += (bytes + 255) & ~(size_t)255; return r;
  };

  const int dN1[6] = {NA, NU, NU, NU, NT, NA};
  const int sN1[6] = {NU, NA, NU, NU, NA, NT};
  const int sN2[3] = {NU, NT, NA};

  // ---- zero-init region: CSR counters + cursors ----
  char* zbase = p;
  CsrArgs ca;
  for (int r = 0; r < 6; ++r) ca.cnt[r] = (int*)alloc((size_t)dN1[r] * 4);
  for (int r = 0; r < 6; ++r) ca.cur[r] = (int*)alloc((size_t)dN1[r] * 4);
  size_t zbytes = (size_t)(p - zbase);

  // ---- non-zero scratch ----
  int* offs[6]; int* csr[6];
  for (int r = 0; r < 6; ++r) {
    offs[r] = (int*)alloc(((size_t)dN1[r] + 1) * 4);
    csr[r]  = (int*)alloc((size_t)E * 4);
    ca.src[r] = ix[2 * r]; ca.dst[r] = ix[2 * r + 1];
    ca.offs[r] = offs[r]; ca.csr[r] = csr[r]; ca.N[r] = dN1[r];
  }
  float* war1  = (float*)alloc(6 * 512 * 4);
  float* war2  = (float*)alloc(3 * 128 * 4);
  float* bcomb = (float*)alloc(512 * 4);
  __hip_bfloat16* zs1[6]; float* el1[6];
  for (int r = 0; r < 6; ++r) {
    zs1[r] = (__hip_bfloat16*)alloc((size_t)sN1[r] * 128 * 2);
    el1[r] = (float*)alloc((size_t)sN1[r] * 4 * 4);
  }
  float* hU  = (float*)alloc((size_t)NU * 128 * 4);
  float* hA  = (float*)alloc((size_t)NA * 128 * 4);
  float* hT  = (float*)alloc((size_t)NT * 128 * 4);
  __hip_bfloat16* zs2[3]; float* el2[3];
  for (int r = 0; r < 3; ++r) {
    zs2[r] = (__hip_bfloat16*)alloc((size_t)sN2[r] * 64 * 2);
    el2[r] = (float*)alloc((size_t)sN2[r] * 4);
  }
  float* h2a = (float*)alloc((size_t)NA * 64 * 4);
  float* h2t = (float*)alloc((size_t)NT * 64 * 4);

  hipMemsetAsync(zbase, 0, zbytes, stream);

  // ---- prep + CSR build ----
  prep<<<10, 256, 0, stream>>>(W1, ar1, b1, W2, ar2, b2, war1, war2, bcomb);
  const int EB4 = (E + 1023) / 1024;
  hist_all<<<6 * EB4, 256, 0, stream>>>(ca, E, EB4);
  scan_all<<<6, 1024, 0, stream>>>(ca);
  scatter_all<<<6 * EB4, 256, 0, stream>>>(ca, E, EB4);

  // ---- layer 1: batched src projections (Z bf16 + el) ----
  {
    GemmB g;
    const float* sF1[6] = {fUser, fArt, fUser, fUser, fArt, fTag};
    int pre = 0;
    for (int r = 0; r < 6; ++r) {
      g.A[r] = sF1[r];
      g.W[r] = W1 + (size_t)r * 16384;
      g.al[r] = al1 + r * 128;
      g.Z[r] = zs1[r];
      g.el[r] = el1[r];
      g.N[r] = sN1[r];
      g.pre[r] = pre;
      pre += (sN1[r] + 15) / 16;
    }
    gemm_batch<128, 128, 4, 8><<<pre, 256, 0, stream>>>(g);
  }

  // ---- layer 1: fused per-dst-type aggregation ----
  {
    AggP a; // artist: rels 0 (ua), 5 (ta)
    a.offs[0]=offs[0]; a.csr[0]=csr[0]; a.el[0]=el1[0]; a.zs[0]=zs1[0]; a.war[0]=war1+0*512;
    a.offs[1]=offs[5]; a.csr[1]=csr[5]; a.el[1]=el1[5]; a.zs[1]=zs1[5]; a.war[1]=war1+5*512;
    a.offs[2]=nullptr; a.csr[2]=nullptr; a.el[2]=nullptr; a.zs[2]=nullptr; a.war[2]=nullptr;
    a.bias = bcomb + 128; a.dfeat = fArt; a.out = hA; a.Nd = NA;
    agg_multi<4, 2, 2><<<(NA + 3) / 4, 256, 0, stream>>>(a);
  }
  {
    AggP a; // user: rels 1 (au), 2 (uu0), 3 (uu1)
    a.offs[0]=offs[1]; a.csr[0]=csr[1]; a.el[0]=el1[1]; a.zs[0]=zs1[1]; a.war[0]=war1+1*512;
    a.offs[1]=offs[2]; a.csr[1]=csr[2]; a.el[1]=el1[2]; a.zs[1]=zs1[2]; a.war[1]=war1+2*512;
    a.offs[2]=offs[3]; a.csr[2]=csr[3]; a.el[2]=el1[3]; a.zs[2]=zs1[3]; a.war[2]=war1+3*512;
    a.bias = bcomb; a.dfeat = fUser; a.out = hU; a.Nd = NU;
    agg_multi<4, 2, 3><<<(NU + 3) / 4, 256, 0, stream>>>(a);
  }
  {
    AggP a; // tag: rel 4 (at)
    a.offs[0]=offs[4]; a.csr[0]=csr[4]; a.el[0]=el1[4]; a.zs[0]=zs1[4]; a.war[0]=war1+4*512;
    a.offs[1]=nullptr; a.csr[1]=nullptr; a.el[1]=nullptr; a.zs[1]=nullptr; a.war[1]=nullptr;
    a.offs[2]=nullptr; a.csr[2]=nullptr; a.el[2]=nullptr; a.zs[2]=nullptr; a.war[2]=nullptr;
    a.bias = bcomb + 256; a.dfeat = fTag; a.out = hT; a.Nd = NT;
    agg_multi<4, 2, 1><<<(NT + 3) / 4, 256, 0, stream>>>(a);
  }

  // ---- layer 2: batched src projections ----
  {
    GemmB g;
    const float* sF2[3] = {hU, hT, hA};
    const int W2i[3] = {0, 5, 4};
    int pre = 0;
    for (int r = 0; r < 3; ++r) {
      g.A[r] = sF2[r];
      g.W[r] = W2 + (size_t)W2i[r] * 8192;
      g.al[r] = al2 + W2i[r] * 64;
      g.Z[r] = zs2[r];
      g.el[r] = el2[r];
      g.N[r] = sN2[r];
      g.pre[r] = pre;
      pre += (sN2[r] + 31) / 32;
    }
    for (int r = 3; r < 6; ++r) {  // unused slots: unreachable prefix
      g.A[r] = nullptr; g.W[r] = nullptr; g.al[r] = nullptr;
      g.Z[r] = nullptr; g.el[r] = nullptr; g.N[r] = 0; g.pre[r] = 0x7fffffff;
    }
    gemm_batch<128, 64, 1, 8><<<pre, 256, 0, stream>>>(g);
  }

  // ---- layer 2: fused aggregation (reuses CSRs 0/5/4) ----
  {
    AggP a; // h2_artist: rels ua (csr0) + ta (csr5)
    a.offs[0]=offs[0]; a.csr[0]=csr[0]; a.el[0]=el2[0]; a.zs[0]=zs2[0]; a.war[0]=war2+0*128;
    a.offs[1]=offs[5]; a.csr[1]=csr[5]; a.el[1]=el2[1]; a.zs[1]=zs2[1]; a.war[1]=war2+1*128;
    a.offs[2]=nullptr; a.csr[2]=nullptr; a.el[2]=nullptr; a.zs[2]=nullptr; a.war[2]=nullptr;
    a.bias = bcomb + 384; a.dfeat = hA; a.out = h2a; a.Nd = NA;
    agg_multi<1, 1, 2><<<(NA + 3) / 4, 256, 0, stream>>>(a);
  }
  {
    AggP a; // h2_tag: rel at (csr4)
    a.offs[0]=offs[4]; a.csr[0]=csr[4]; a.el[0]=el2[2]; a.zs[0]=zs2[2]; a.war[0]=war2+2*128;
    a.offs[1]=nullptr; a.csr[1]=nullptr; a.el[1]=nullptr; a.zs[1]=nullptr; a.war[1]=nullptr;
    a.offs[2]=nullptr; a.csr[2]=nullptr; a.el[2]=nullptr; a.zs[2]=nullptr; a.war[2]=nullptr;
    a.bias = bcomb + 448; a.dfeat = hT; a.out = h2t; a.Nd = NT;
    agg_multi<1, 1, 1><<<(NT + 3) / 4, 256, 0, stream>>>(a);
  }

  // ---- predictor ----
  pred_dot<<<(int)(((size_t)(E + EN) * 16 + 255) / 256), 256, 0, stream>>>(
      h2a, h2t, ix[8], ix[9], ix[12], ix[13], (float*)d_out, E, EN);
}